// Round 8
// baseline (402.220 us; speedup 1.0000x reference)
//
#include <hip/hip_runtime.h>

typedef __attribute__((ext_vector_type(8))) short bf16x8;
typedef __attribute__((ext_vector_type(4))) short bf16x4;
typedef __attribute__((ext_vector_type(4))) float f32x4;
typedef __attribute__((ext_vector_type(2))) float f32x2;
typedef __attribute__((ext_vector_type(16))) float f32x16;

#define BATCH 2
#define CH    512
#define NPIX  4096
#define NSP   4
#define SPK   1024   // keys per split
#define KT    32     // keys per tile

__device__ __forceinline__ unsigned short f2b(float f) {
    unsigned int u; __builtin_memcpy(&u, &f, 4);
    u = u + 0x7FFFu + ((u >> 16) & 1u);   // RNE
    return (unsigned short)(u >> 16);
}
__device__ __forceinline__ float b2f(unsigned short h) {
    unsigned int u = ((unsigned int)h) << 16;
    float f; __builtin_memcpy(&f, &u, 4);
    return f;
}
// async 16B/lane global->LDS (wave-uniform LDS base, per-lane global src)
__device__ __forceinline__ void gll16(void* lds, const void* g) {
    __builtin_amdgcn_global_load_lds(
        (const __attribute__((address_space(1))) void*)g,
        (__attribute__((address_space(3))) void*)lds, 16, 0, 0);
}

// ---------------------------------------------------------------- fp32 -> bf16 weight convert
__global__ __launch_bounds__(256) void convert_kernel(
    const float* __restrict__ qkv_w, const float* __restrict__ proj_w,
    unsigned short* __restrict__ wbf)
{
    int i = blockIdx.x * 256 + threadIdx.x;            // grid covers 1048576
    float v = (i < 786432) ? qkv_w[i] : proj_w[i - 786432];
    wbf[i] = f2b(v);
}

// ---------------------------------------------------------------- GN stats (2-stage, parallel)
__global__ __launch_bounds__(256) void stats1_kernel(
    const float* __restrict__ x, f32x2* __restrict__ part)
{
    int id = blockIdx.x;            // 256 blocks: bg*4 + quarter
    int bg = id >> 2, q = id & 3;
    int b = bg >> 5, g = bg & 31;
    const float* xp = x + ((size_t)b * CH + (size_t)g * 16 + q * 4) * NPIX;
    float s = 0.f, ss = 0.f;
    for (int i = threadIdx.x; i < 4 * NPIX; i += 256) {
        float v = xp[i]; s += v; ss += v * v;
    }
    for (int off = 32; off; off >>= 1) {
        s  += __shfl_down(s,  off, 64);
        ss += __shfl_down(ss, off, 64);
    }
    __shared__ float red[2][4];
    int wv = threadIdx.x >> 6;
    if ((threadIdx.x & 63) == 0) { red[0][wv] = s; red[1][wv] = ss; }
    __syncthreads();
    if (threadIdx.x == 0) {
        s  = red[0][0] + red[0][1] + red[0][2] + red[0][3];
        ss = red[1][0] + red[1][1] + red[1][2] + red[1][3];
        part[id] = (f32x2){s, ss};
    }
}

__global__ __launch_bounds__(64) void stats2_kernel(
    const f32x2* __restrict__ part, float* __restrict__ stats)
{
    int t = threadIdx.x;            // 64 = b*32+g
    float s = 0.f, ss = 0.f;
    #pragma unroll
    for (int q = 0; q < 4; q++) { f32x2 p = part[t * 4 + q]; s += p[0]; ss += p[1]; }
    const float inv = 1.f / (16 * NPIX);
    float mean = s * inv;
    float var  = ss * inv - mean * mean;
    stats[t * 2 + 0] = mean;
    stats[t * 2 + 1] = rsqrtf(var + 1e-6f);
}

// ---------------------------------------------------------------- Q/K/V GEMM + fused GroupNorm
// grid (64, 2, 3) = 384 blocks, 2 blocks/CU. third 0->Q (scaled), 1->K, 2->V.
// V stored PI16-PERMUTED within each 16-key group: stored pos s holds key
// k: s(k) = (k&3) | (((k>>3)&1)<<2) | (((k>>2)&1)<<3)  (i.e. order 0-3,8-11,4-7,12-15)
// -> attn PV A-frag = one contiguous 16B read per lane (32x32x16 k-slot order).
__global__ __launch_bounds__(256, 2) void qkv_kernel(
    const float* __restrict__ x,
    const unsigned short* __restrict__ wbf,  // bf16 qkv_w [1536][512]
    const float* __restrict__ bias,
    const float* __restrict__ gamma,
    const float* __restrict__ beta,
    const float* __restrict__ stats,
    unsigned short* __restrict__ Q,          // [b][n][c] pre-scaled
    unsigned short* __restrict__ K,          // [b][n][c]
    unsigned short* __restrict__ V)          // [b][c][grp16][16 permuted]
{
    __shared__ unsigned short hn[64][520];
    int b     = blockIdx.y;
    int third = blockIdx.z;
    int m0    = blockIdx.x * 64;
    int tid = threadIdx.x;
    {   // stage + normalize: p4 = (tid&15)*4 (4 pixels), cg = tid>>4 (16 ch slots)
        const float* xb = x + (size_t)b * CH * NPIX + m0;
        const float* st = stats + b * 64;
        int p4 = (tid & 15) * 4, cg = tid >> 4;
        for (int c0 = 0; c0 < CH; c0 += 16) {
            int c = c0 + cg;
            float mean = st[(c >> 4) * 2 + 0];
            float rstd = st[(c >> 4) * 2 + 1];
            float ga = gamma[c] * rstd;
            float be = beta[c] - mean * ga;
            f32x4 v = *(const f32x4*)(xb + (size_t)c * NPIX + p4);
            hn[p4 + 0][c] = f2b(v[0] * ga + be);
            hn[p4 + 1][c] = f2b(v[1] * ga + be);
            hn[p4 + 2][c] = f2b(v[2] * ga + be);
            hn[p4 + 3][c] = f2b(v[3] * ga + be);
        }
    }
    __syncthreads();

    int wv = tid >> 6, lane = tid & 63, ln = lane & 15, quad = lane >> 4;
    const float scale = 0.04419417382415922f;  // 512^-0.5
    #pragma unroll
    for (int nt = 0; nt < 8; nt++) {
        int o = nt * 64 + wv * 16 + ln;            // [0, 512)
        int row = third * 512 + o;
        const unsigned short* bp = wbf + (size_t)row * CH + quad * 8;
        bf16x8 wf[16];
        #pragma unroll
        for (int k = 0; k < 16; k++) wf[k] = *(const bf16x8*)(bp + k * 32);
        float bi = bias[row];
        #pragma unroll
        for (int qt = 0; qt < 4; qt++) {
            f32x4 acc = {0.f, 0.f, 0.f, 0.f};
            #pragma unroll
            for (int k = 0; k < 16; k++) {
                bf16x8 a = *(const bf16x8*)(&hn[qt * 16 + ln][quad * 8 + k * 32]);
                acc = __builtin_amdgcn_mfma_f32_16x16x32_bf16(a, wf[k], acc, 0, 0, 0);
            }
            int m = m0 + qt * 16 + quad * 4;
            if (third == 0) {
                #pragma unroll
                for (int r = 0; r < 4; r++)
                    Q[((size_t)b * NPIX + m + r) * CH + o] = f2b((acc[r] + bi) * scale);
            } else if (third == 1) {
                #pragma unroll
                for (int r = 0; r < 4; r++)
                    K[((size_t)b * NPIX + m + r) * CH + o] = f2b(acc[r] + bi);
            } else {
                bf16x4 pk;
                #pragma unroll
                for (int r = 0; r < 4; r++) pk[r] = f2b(acc[r] + bi);
                // keys m..m+3: within 16-group, stored base = pi16(quad*4)
                int grp = m & ~15;
                int sb  = ((quad >> 1) << 2) | ((quad & 1) << 3);
                *(bf16x4*)(V + ((size_t)b * CH + o) * NPIX + grp + sb) = pk;
            }
        }
    }
}

// ---------------------------------------------------------------- attention: 32x32 in-register flash
// 256 blocks x 512 thr (8 waves), 1 block/CU. bid&7 = XCD -> (b,sp): per-XCD
// K+V = 2MB (fits L2). Block = 128 queries; wave (qg,cs) = 32 queries x 256-ch half.
// S = mfma_32x32x16(K, Q): lane holds 16 S of query (lane&31) -> softmax needs one
// shfl_xor(32); P B-frag = lane's own S regs packed (pi16 V-permutation makes the
// k-slot order line up) -> zero cross-lane ops in PV. cs-pair exchanges S-partials
// via 32KB LDS. Sync skeleton identical to round 7 (3 barriers, counted vmcnt).
__global__ __launch_bounds__(512, 2) void attn_kernel(
    const unsigned short* __restrict__ Qg,   // [b][n][c] bf16, pre-scaled
    const unsigned short* __restrict__ Kg,   // [b][n][c]
    const unsigned short* __restrict__ Vg,   // [b][c][grp16][16 perm]
    unsigned short* __restrict__ Opart,      // [b][sp][n][c] bf16 numerators
    float* __restrict__ ml)                  // [b][sp][n][2] f32
{
    // LDS 128KB: K dbuf 2x32K @0 ([32 keyrows][64 chunks16], chunk p holds global
    // chunk p^(row&7)); V 32K @65536 ([512 chrows][4 chunks16], chunk p holds
    // global chunk p^(row&3)); SX 32K @98304 ([8 waves][4 quarters][64 lanes x16B]).
    __shared__ __align__(16) char sm[131072];
    char* const KB0 = sm;
    char* const KB1 = sm + 32768;
    char* const VB  = sm + 65536;
    char* const SX  = sm + 98304;

    int bid = blockIdx.x;
    int xcd = bid & 7;
    int b  = xcd >> 2;
    int sp = xcd & 3;
    int q0 = (bid >> 3) << 7;                // 32 query-tiles of 128
    int tid = threadIdx.x;
    int wv = tid >> 6, lane = tid & 63;
    int qg = wv >> 1, cs = wv & 1;           // query group (32q), channel half (256c)
    int rL = lane & 31, hl = lane >> 5;

    const unsigned short* K = Kg + ((size_t)b * NPIX + (size_t)sp * SPK) * CH;
    const unsigned short* V = Vg + (size_t)b * CH * NPIX + (size_t)sp * SPK;
    const unsigned short* Qp = Qg + ((size_t)(b * NPIX + q0 + qg * 32)) * CH;

    // K stage: 4 rows/wave; row r: LDS chunk p holds global chunk p^(r&7)
    auto stageK = [&](char* buf, int kb) {
        #pragma unroll
        for (int j = 0; j < 4; j++) {
            int r = wv * 4 + j;
            gll16(buf + r * 1024,
                  K + (size_t)(kb + r) * CH + ((lane ^ (r & 7)) << 3));
        }
    };
    // V stage: 64 ch-rows/wave; row ch: LDS chunk p holds global chunk p^(ch&3)
    auto stageV = [&](int kb) {
        #pragma unroll
        for (int j = 0; j < 4; j++) {
            int r0 = wv * 64 + j * 16;
            int ch = r0 + (lane >> 2);
            gll16(VB + r0 * 64,
                  V + (size_t)ch * NPIX + kb + (((lane & 3) ^ (ch & 3)) << 3));
        }
    };

    // ---- prologue: K(0), qf (16 B-frags: Q[32q][256ch half]), V(0)
    stageK(KB0, 0);
    bf16x8 qf[16];
    #pragma unroll
    for (int s = 0; s < 16; s++)
        qf[s] = *(const bf16x8*)(Qp + (size_t)rL * CH + cs * 256 + s * 16 + hl * 8);
    stageV(0);
    asm volatile("s_waitcnt vmcnt(4)" ::: "memory");   // K(0)+qf drained; V(0) in flight

    // K read: addr = KBc + rL*1024 + ((aK + 2s) ^ swzK)<<4
    const int kbase = rL * 1024;
    const int aK   = cs * 32 + hl;      // bits {0,5}; 2s uses bits 1-4 (no carry)
    const int swzK = rL & 7;
    // V read: addr = VB + (cs*256 + vb*32 + rL)*64 + (cV ^ (mfma#*32))
    const int vbase = (cs * 256 + rL) * 64;
    const int cV = (hl ^ (rL & 3)) << 4;
    // SX: own slot (wv*4+c)*1024 + lane*16; partner = wv^1 (cs flipped)
    const int sxw = wv * 4096 + lane * 16;
    const int sxr = (wv ^ 1) * 4096 + lane * 16;

    f32x16 O[8];
    #pragma unroll
    for (int i = 0; i < 8; i++)
        #pragma unroll
        for (int r = 0; r < 16; r++) O[i][r] = 0.f;
    float m_reg = -1e30f, l_reg = 0.f;

    for (int it = 0; it < SPK / KT; ++it) {
        char* const KBc = (it & 1) ? KB1 : KB0;
        char* const KBn = (it & 1) ? KB0 : KB1;
        int nkb = ((it + 1) * KT) & (SPK - 1);   // last iter wraps: harmless dummy

        // (1) stage next K tile (in flight across the whole iteration)
        stageK(KBn, nkb);

        // (2) queue = [K(it) 4][V(it) 4][K(it+1) 4]; vmcnt(8) ==> K(it) landed
        asm volatile("s_waitcnt vmcnt(8)" ::: "memory");
        __builtin_amdgcn_s_barrier();

        // (3) S partial = mfma_32x32x16(K, Q) over this wave's 256-ch half
        f32x16 S;
        #pragma unroll
        for (int r = 0; r < 16; r++) S[r] = 0.f;
        __builtin_amdgcn_s_setprio(1);
        #pragma unroll
        for (int s = 0; s < 16; s++) {
            bf16x8 kf = *(const bf16x8*)(KBc + kbase + (((aK + 2 * s) ^ swzK) << 4));
            S = __builtin_amdgcn_mfma_f32_32x32x16_bf16(kf, qf[s], S, 0, 0, 0);
        }
        __builtin_amdgcn_s_setprio(0);

        // (4) exchange partials with cs-partner; vmcnt(4) also gates V(it)
        *(f32x4*)(SX + sxw +  0) = (f32x4){S[0],  S[1],  S[2],  S[3]};
        *(f32x4*)(SX + sxw + 1024) = (f32x4){S[4],  S[5],  S[6],  S[7]};
        *(f32x4*)(SX + sxw + 2048) = (f32x4){S[8],  S[9],  S[10], S[11]};
        *(f32x4*)(SX + sxw + 3072) = (f32x4){S[12], S[13], S[14], S[15]};
        asm volatile("s_waitcnt vmcnt(4) lgkmcnt(0)" ::: "memory");
        __builtin_amdgcn_s_barrier();
        {
            f32x4 p0 = *(const f32x4*)(SX + sxr +  0);
            f32x4 p1 = *(const f32x4*)(SX + sxr + 1024);
            f32x4 p2 = *(const f32x4*)(SX + sxr + 2048);
            f32x4 p3 = *(const f32x4*)(SX + sxr + 3072);
            #pragma unroll
            for (int r = 0; r < 4; r++) {
                S[r]      += p0[r];
                S[r + 4]  += p1[r];
                S[r + 8]  += p2[r];
                S[r + 12] += p3[r];
            }
        }

        // (5) in-register online softmax (query = lane&31; halves pair via xor 32)
        float mx = S[0];
        #pragma unroll
        for (int r = 1; r < 16; r++) mx = fmaxf(mx, S[r]);
        mx = fmaxf(mx, __shfl_xor(mx, 32, 64));
        if (!__all(mx <= m_reg + 8.f)) {
            float mnew  = fmaxf(m_reg, mx);
            float alpha = __expf(m_reg - mnew);
            l_reg *= alpha;
            #pragma unroll
            for (int i = 0; i < 8; i++)
                #pragma unroll
                for (int r = 0; r < 16; r++) O[i][r] *= alpha;
            m_reg = mnew;
        }
        float e[16];
        #pragma unroll
        for (int r = 0; r < 16; r++) e[r] = __expf(S[r] - m_reg);
        float ts = 0.f;
        #pragma unroll
        for (int r = 0; r < 16; r++) ts += e[r];
        ts += __shfl_xor(ts, 32, 64);
        l_reg += ts;
        bf16x8 pf0, pf1;
        #pragma unroll
        for (int r = 0; r < 8; r++) { pf0[r] = f2b(e[r]); pf1[r] = f2b(e[r + 8]); }

        // (6) PV: per 32-ch block: A = V-frag (16B LDS read), B = pf0/pf1
        __builtin_amdgcn_s_setprio(1);
        #pragma unroll
        for (int vb = 0; vb < 8; vb++) {
            bf16x8 v0 = *(const bf16x8*)(VB + vbase + vb * 2048 + cV);
            bf16x8 v1 = *(const bf16x8*)(VB + vbase + vb * 2048 + (cV ^ 32));
            O[vb] = __builtin_amdgcn_mfma_f32_32x32x16_bf16(v0, pf0, O[vb], 0, 0, 0);
            O[vb] = __builtin_amdgcn_mfma_f32_32x32x16_bf16(v1, pf1, O[vb], 0, 0, 0);
        }
        __builtin_amdgcn_s_setprio(0);

        // (7) all waves' V/SX reads done -> safe to overwrite VB
        asm volatile("s_waitcnt lgkmcnt(0)" ::: "memory");
        __builtin_amdgcn_s_barrier();

        // (8) stage next V tile into the single buffer
        stageV(nkb);
    }
    asm volatile("s_waitcnt vmcnt(0)" ::: "memory");   // drain dummy stages before exit

    // ---- store partial O numerators + m,l
    // reg r of O[vb] -> ch = cs*256 + vb*32 + (r&3) + 8*(r>>2) + 4*hl ; query = rL
    size_t n = (size_t)(b * NSP + sp) * NPIX + q0 + qg * 32 + rL;
    unsigned short* Ob = Opart + n * CH + cs * 256 + hl * 4;
    #pragma unroll
    for (int vb = 0; vb < 8; vb++) {
        #pragma unroll
        for (int j = 0; j < 4; j++) {
            bf16x4 pk;
            #pragma unroll
            for (int r = 0; r < 4; r++) pk[r] = f2b(O[vb][j * 4 + r]);
            *(bf16x4*)(Ob + vb * 32 + j * 8) = pk;
        }
    }
    if (cs == 0 && hl == 0) {
        ml[n * 2 + 0] = m_reg;
        ml[n * 2 + 1] = l_reg;
    }
}

// ---------------------------------------------------------------- merge 4 splits + proj + residual
__global__ __launch_bounds__(512, 2) void merge_kernel(
    const float* __restrict__ x,
    const unsigned short* __restrict__ Opart,
    const float* __restrict__ ml,
    const unsigned short* __restrict__ pw,   // bf16 proj_w [512][512]
    const float* __restrict__ pb,
    float* __restrict__ out)
{
    __shared__ __align__(16) unsigned short ao[32][520];
    int b  = blockIdx.y;
    int q0 = blockIdx.x * 32;
    int tid = threadIdx.x;
    int wv = tid >> 6, lane = tid & 63, ln = lane & 15, quad = lane >> 4;

    {   // combine splits: p = tid&31 (pixel), cs = tid>>5 (16 slots of 8ch)
        int p = tid & 31, cs = tid >> 5;
        int n = q0 + p;
        float m[NSP], l[NSP];
        #pragma unroll
        for (int s = 0; s < NSP; s++) {
            size_t i = ((size_t)(b * NSP + s) * NPIX + n) * 2;
            m[s] = ml[i]; l[s] = ml[i + 1];
        }
        float M = fmaxf(fmaxf(m[0], m[1]), fmaxf(m[2], m[3]));
        float w[NSP]; float den = 0.f;
        #pragma unroll
        for (int s = 0; s < NSP; s++) { w[s] = __expf(m[s] - M); den += l[s] * w[s]; }
        float dinv = 1.f / den;
        #pragma unroll
        for (int s = 0; s < NSP; s++) w[s] *= dinv;
        #pragma unroll
        for (int k = 0; k < 4; k++) {
            int c = cs * 8 + k * 128;
            float acc8[8] = {0.f,0.f,0.f,0.f,0.f,0.f,0.f,0.f};
            #pragma unroll
            for (int s = 0; s < NSP; s++) {
                const unsigned short* Os = Opart + ((size_t)(b * NSP + s) * NPIX + n) * CH;
                bf16x8 a = *(const bf16x8*)(Os + c);
                #pragma unroll
                for (int j = 0; j < 8; j++) acc8[j] += b2f((unsigned short)a[j]) * w[s];
            }
            #pragma unroll
            for (int j = 0; j < 8; j++) ao[p][c + j] = f2b(acc8[j]);
        }
    }
    __syncthreads();

    // ---- proj: out channels [wv*64,+64) + bias + residual (fp32)
    #pragma unroll
    for (int nt = 0; nt < 4; nt++) {
        int o = wv * 64 + nt * 16 + ln;
        const unsigned short* bp = pw + (size_t)o * CH + quad * 8;
        bf16x8 wf[16];
        #pragma unroll
        for (int k = 0; k < 16; k++) wf[k] = *(const bf16x8*)(bp + k * 32);
        float bi = pb[o];
        #pragma unroll
        for (int qt = 0; qt < 2; qt++) {
            f32x4 acc = {0.f, 0.f, 0.f, 0.f};
            #pragma unroll
            for (int k = 0; k < 16; k++) {
                bf16x8 a = *(const bf16x8*)(&ao[qt * 16 + ln][quad * 8 + k * 32]);
                acc = __builtin_amdgcn_mfma_f32_16x16x32_bf16(a, wf[k], acc, 0, 0, 0);
            }
            size_t base = ((size_t)b * CH + o) * NPIX + q0 + qt * 16 + quad * 4;
            f32x4 xin = *(const f32x4*)(x + base);
            f32x4 o4;
            #pragma unroll
            for (int r = 0; r < 4; r++) o4[r] = xin[r] + acc[r] + bi;
            *(f32x4*)(out + base) = o4;
        }
    }
}

// ----------------------------------------------------------------
extern "C" void kernel_launch(void* const* d_in, const int* in_sizes, int n_in,
                              void* d_out, int out_size, void* d_ws, size_t ws_size,
                              hipStream_t stream)
{
    const float* x      = (const float*)d_in[0];
    const float* gn_g   = (const float*)d_in[1];
    const float* gn_b   = (const float*)d_in[2];
    const float* qkv_w  = (const float*)d_in[3];
    const float* qkv_b  = (const float*)d_in[4];
    const float* proj_w = (const float*)d_in[5];
    const float* proj_b = (const float*)d_in[6];
    float* out = (float*)d_out;

    // Workspace (shorts): K 4M | V 4M | Q 4M | wbf 1M | stats/part/ml | Opart 16M (~58.5MB)
    unsigned short* ws  = (unsigned short*)d_ws;
    unsigned short* Kb  = ws;                           // [2][4096][512]
    unsigned short* Vb  = ws + 4u * 1024 * 1024;        // [2][512][4096] (pi16-permuted)
    unsigned short* Qb  = ws + 8u * 1024 * 1024;        // [2][4096][512] (scaled)
    unsigned short* wbf = ws + 12u * 1024 * 1024;       // qkv_w | proj_w bf16
    unsigned short* wp  = wbf + 786432;
    float* stats = (float*)(ws + 13u * 1024 * 1024);             // 128 f32
    f32x2* part  = (f32x2*)(ws + 13u * 1024 * 1024 + 1024);      // 256 f32x2
    float* ml    = (float*)(ws + 13u * 1024 * 1024 + 4096);      // [2][4][4096][2] f32
    unsigned short* Opart = ws + 13u * 1024 * 1024 + 4096 + 262144;

    convert_kernel<<<dim3(1048576 / 256), 256, 0, stream>>>(qkv_w, proj_w, wbf);
    stats1_kernel <<<dim3(256), 256, 0, stream>>>(x, part);
    stats2_kernel <<<dim3(1), 64, 0, stream>>>(part, stats);
    qkv_kernel    <<<dim3(NPIX / 64, BATCH, 3), 256, 0, stream>>>(
        x, wbf, qkv_b, gn_g, gn_b, stats, Qb, Kb, Vb);
    attn_kernel   <<<dim3(256), 512, 0, stream>>>(Qb, Kb, Vb, Opart, ml);
    merge_kernel  <<<dim3(NPIX / 32, BATCH), 512, 0, stream>>>(
        x, Opart, ml, wp, proj_b, out);
}

// Round 10
// 382.166 us; speedup vs baseline: 1.0525x; 1.0525x over previous
//
#include <hip/hip_runtime.h>

typedef __attribute__((ext_vector_type(8))) short bf16x8;
typedef __attribute__((ext_vector_type(4))) short bf16x4;
typedef __attribute__((ext_vector_type(4))) float f32x4;
typedef __attribute__((ext_vector_type(2))) float f32x2;

#define BATCH 2
#define CH    512
#define NPIX  4096
#define NSP   4
#define SPK   1024   // keys per split
#define KT    32     // keys per tile

__device__ __forceinline__ unsigned short f2b(float f) {
    unsigned int u; __builtin_memcpy(&u, &f, 4);
    u = u + 0x7FFFu + ((u >> 16) & 1u);   // RNE
    return (unsigned short)(u >> 16);
}
__device__ __forceinline__ float b2f(unsigned short h) {
    unsigned int u = ((unsigned int)h) << 16;
    float f; __builtin_memcpy(&f, &u, 4);
    return f;
}
// async 16B/lane global->LDS (wave-uniform LDS base, per-lane global src)
__device__ __forceinline__ void gll16(void* lds, const void* g) {
    __builtin_amdgcn_global_load_lds(
        (const __attribute__((address_space(1))) void*)g,
        (__attribute__((address_space(3))) void*)lds, 16, 0, 0);
}

// ---------------------------------------------------------------- fp32 -> bf16 weight convert
__global__ __launch_bounds__(256) void convert_kernel(
    const float* __restrict__ qkv_w, const float* __restrict__ proj_w,
    unsigned short* __restrict__ wbf)
{
    int i = blockIdx.x * 256 + threadIdx.x;            // grid covers 1048576
    float v = (i < 786432) ? qkv_w[i] : proj_w[i - 786432];
    wbf[i] = f2b(v);
}

// ---------------------------------------------------------------- GN stats (2-stage, parallel)
__global__ __launch_bounds__(256) void stats1_kernel(
    const float* __restrict__ x, f32x2* __restrict__ part)
{
    int id = blockIdx.x;            // 256 blocks: bg*4 + quarter
    int bg = id >> 2, q = id & 3;
    int b = bg >> 5, g = bg & 31;
    const float* xp = x + ((size_t)b * CH + (size_t)g * 16 + q * 4) * NPIX;
    float s = 0.f, ss = 0.f;
    for (int i = threadIdx.x; i < 4 * NPIX; i += 256) {
        float v = xp[i]; s += v; ss += v * v;
    }
    for (int off = 32; off; off >>= 1) {
        s  += __shfl_down(s,  off, 64);
        ss += __shfl_down(ss, off, 64);
    }
    __shared__ float red[2][4];
    int wv = threadIdx.x >> 6;
    if ((threadIdx.x & 63) == 0) { red[0][wv] = s; red[1][wv] = ss; }
    __syncthreads();
    if (threadIdx.x == 0) {
        s  = red[0][0] + red[0][1] + red[0][2] + red[0][3];
        ss = red[1][0] + red[1][1] + red[1][2] + red[1][3];
        part[id] = (f32x2){s, ss};
    }
}

__global__ __launch_bounds__(64) void stats2_kernel(
    const f32x2* __restrict__ part, float* __restrict__ stats)
{
    int t = threadIdx.x;            // 64 = b*32+g
    float s = 0.f, ss = 0.f;
    #pragma unroll
    for (int q = 0; q < 4; q++) { f32x2 p = part[t * 4 + q]; s += p[0]; ss += p[1]; }
    const float inv = 1.f / (16 * NPIX);
    float mean = s * inv;
    float var  = ss * inv - mean * mean;
    stats[t * 2 + 0] = mean;
    stats[t * 2 + 1] = rsqrtf(var + 1e-6f);
}

// ---------------------------------------------------------------- Q/K/V GEMM + fused GroupNorm
// grid (64, 2, 3) = 384 blocks, 2 blocks/CU. third 0->Q (scaled), 1->K, 2->V.
// V stored PI-PERMUTED within each 32-key group (round-7-verified layout):
// stored pos s holds key k(s) = (s>>3)*4 + (s&3) + 16*((s>>2)&1).
__global__ __launch_bounds__(256, 2) void qkv_kernel(
    const float* __restrict__ x,
    const unsigned short* __restrict__ wbf,  // bf16 qkv_w [1536][512]
    const float* __restrict__ bias,
    const float* __restrict__ gamma,
    const float* __restrict__ beta,
    const float* __restrict__ stats,
    unsigned short* __restrict__ Q,          // [b][n][c] pre-scaled
    unsigned short* __restrict__ K,          // [b][n][c]
    unsigned short* __restrict__ V)          // [b][c][grp][32 permuted]
{
    __shared__ unsigned short hn[64][520];
    int b     = blockIdx.y;
    int third = blockIdx.z;
    int m0    = blockIdx.x * 64;
    int tid = threadIdx.x;
    {   // stage + normalize: p4 = (tid&15)*4 (4 pixels), cg = tid>>4 (16 ch slots)
        const float* xb = x + (size_t)b * CH * NPIX + m0;
        const float* st = stats + b * 64;
        int p4 = (tid & 15) * 4, cg = tid >> 4;
        for (int c0 = 0; c0 < CH; c0 += 16) {
            int c = c0 + cg;
            float mean = st[(c >> 4) * 2 + 0];
            float rstd = st[(c >> 4) * 2 + 1];
            float ga = gamma[c] * rstd;
            float be = beta[c] - mean * ga;
            f32x4 v = *(const f32x4*)(xb + (size_t)c * NPIX + p4);
            hn[p4 + 0][c] = f2b(v[0] * ga + be);
            hn[p4 + 1][c] = f2b(v[1] * ga + be);
            hn[p4 + 2][c] = f2b(v[2] * ga + be);
            hn[p4 + 3][c] = f2b(v[3] * ga + be);
        }
    }
    __syncthreads();

    int wv = tid >> 6, lane = tid & 63, ln = lane & 15, quad = lane >> 4;
    const float scale = 0.04419417382415922f;  // 512^-0.5
    #pragma unroll
    for (int nt = 0; nt < 8; nt++) {
        int o = nt * 64 + wv * 16 + ln;            // [0, 512)
        int row = third * 512 + o;
        const unsigned short* bp = wbf + (size_t)row * CH + quad * 8;
        bf16x8 wf[16];
        #pragma unroll
        for (int k = 0; k < 16; k++) wf[k] = *(const bf16x8*)(bp + k * 32);
        float bi = bias[row];
        #pragma unroll
        for (int qt = 0; qt < 4; qt++) {
            f32x4 acc = {0.f, 0.f, 0.f, 0.f};
            #pragma unroll
            for (int k = 0; k < 16; k++) {
                bf16x8 a = *(const bf16x8*)(&hn[qt * 16 + ln][quad * 8 + k * 32]);
                acc = __builtin_amdgcn_mfma_f32_16x16x32_bf16(a, wf[k], acc, 0, 0, 0);
            }
            int m = m0 + qt * 16 + quad * 4;
            if (third == 0) {
                #pragma unroll
                for (int r = 0; r < 4; r++)
                    Q[((size_t)b * NPIX + m + r) * CH + o] = f2b((acc[r] + bi) * scale);
            } else if (third == 1) {
                #pragma unroll
                for (int r = 0; r < 4; r++)
                    K[((size_t)b * NPIX + m + r) * CH + o] = f2b(acc[r] + bi);
            } else {
                bf16x4 pk;
                #pragma unroll
                for (int r = 0; r < 4; r++) pk[r] = f2b(acc[r] + bi);
                int grp = m & ~31;
                int s   = ((m & 15) >> 2) * 8 + ((m >> 4) & 1) * 4;  // pi position
                *(bf16x4*)(V + ((size_t)b * CH + o) * NPIX + grp + s) = pk;
            }
        }
    }
}

// ---------------------------------------------------------------- attention: in-register flash
// 256 blocks x 512 thr (8 waves), 1 block/CU. bid&7 = XCD -> (b,sp): per-XCD
// K+V = 2MB (fits L2). Wave (qg,cs) = 32 QUERIES (two 16q sub-groups qt=0,1)
// x 256-ch half: every kf/vf LDS read now feeds TWO MFMAs -> LDS reads per
// unit work halve vs round 7. S partials over ch-half; cs-pair exchanges via
// 32KB SX. In-register softmax (defer-max THR=8) per qt. Sync skeleton
// identical to round 7: 3 barriers, counted vmcnt (8 for K, 4 for V), no
// drain-0 in the loop.
__global__ __launch_bounds__(512, 2) void attn_kernel(
    const unsigned short* __restrict__ Qg,   // [b][n][c] bf16, pre-scaled
    const unsigned short* __restrict__ Kg,   // [b][n][c]
    const unsigned short* __restrict__ Vg,   // [b][c][grp][32 perm]
    unsigned short* __restrict__ Opart,      // [b][sp][n][c] bf16 numerators
    float* __restrict__ ml)                  // [b][sp][n][2] f32
{
    // LDS 128KB: K dbuf 2x32K @0 ([32 keyrows][64 chunks16], chunk p holds
    // global chunk p^(row&7)); V 32K @65536 ([512 chrows][4 chunks16], chunk p
    // holds global chunk p^((row>>1)&3)); SX 32K @98304 (cs-pair S exchange,
    // 128 rows x 256B: row = wv*16+ln, qt selects bit7).
    __shared__ __align__(16) char sm[131072];
    char* const KB0 = sm;
    char* const KB1 = sm + 32768;
    char* const VB  = sm + 65536;
    char* const SX  = sm + 98304;

    int bid = blockIdx.x;
    int xcd = bid & 7;
    int b  = xcd >> 2;
    int sp = xcd & 3;
    int q0 = (bid >> 3) << 7;                // 32 query-tiles of 128
    int tid = threadIdx.x;
    int wv = tid >> 6, lane = tid & 63, ln = lane & 15, quad = lane >> 4;
    int qg = wv >> 1, cs = wv & 1;           // wave query-group (32q), channel half

    const unsigned short* K = Kg + ((size_t)b * NPIX + (size_t)sp * SPK) * CH;
    const unsigned short* V = Vg + (size_t)b * CH * NPIX + (size_t)sp * SPK;
    const unsigned short* Qp = Qg + ((size_t)(b * NPIX + q0 + qg * 32)) * CH;

    // K stage: 4 rows/wave; row r: LDS chunk p holds global chunk p^(r&7)
    auto stageK = [&](char* buf, int kb) {
        #pragma unroll
        for (int j = 0; j < 4; j++) {
            int r = wv * 4 + j;
            gll16(buf + r * 1024,
                  K + (size_t)(kb + r) * CH + ((lane ^ (r & 7)) << 3));
        }
    };
    // V stage: 64 ch-rows/wave; row ch: LDS chunk p holds global chunk p^((ch>>1)&3)
    auto stageV = [&](int kb) {
        #pragma unroll
        for (int j = 0; j < 4; j++) {
            int r0 = wv * 64 + j * 16;
            int ch = r0 + (lane >> 2);
            gll16(VB + r0 * 64,
                  V + (size_t)ch * NPIX + kb + (((lane & 3) ^ ((ch >> 1) & 3)) << 3));
        }
    };

    // ---- prologue: K(0), qf for both 16q sub-groups (this wave's ch-half), V(0)
    stageK(KB0, 0);
    bf16x8 qf0[8], qf1[8];
    #pragma unroll
    for (int kt = 0; kt < 8; kt++) {
        qf0[kt] = *(const bf16x8*)(Qp + (size_t)ln * CH + cs * 256 + kt * 32 + quad * 8);
        qf1[kt] = *(const bf16x8*)(Qp + (size_t)(16 + ln) * CH + cs * 256 + kt * 32 + quad * 8);
    }
    stageV(0);

    // K LDS read base (swizzle folded; + cs half offset)
    const int BK = ln * 1024 + ((quad ^ (ln & 3)) << 4) + (((ln >> 2) & 1) << 6) + cs * 512;
    // V LDS read base (row = cs*256 + ct*16 + ln)
    const int BV = (cs * 256 + ln) * 64 + ((quad ^ ((ln >> 1) & 3)) << 4);
    // SX: row (wv*16+ln) x 256B; within row: qt bit7, half bit4-flip, quad-spread
    const int sxo = ((quad ^ (ln & 3)) << 5) + (((ln >> 2) & 1) << 4);
    const int sxw = ((wv * 16 + ln) << 8) + sxo;         // own slot
    const int sxr = (((wv ^ 1) * 16 + ln) << 8) + sxo;   // partner (cs flipped)

    f32x4 O0[16], O1[16];
    #pragma unroll
    for (int i = 0; i < 16; i++) {
        O0[i] = (f32x4){0.f, 0.f, 0.f, 0.f};
        O1[i] = (f32x4){0.f, 0.f, 0.f, 0.f};
    }
    float m0_reg = -1e30f, l0_reg = 0.f;
    float m1_reg = -1e30f, l1_reg = 0.f;

    for (int it = 0; it < SPK / KT; ++it) {
        char* const KBc = (it & 1) ? KB1 : KB0;
        char* const KBn = (it & 1) ? KB0 : KB1;
        int nkb = ((it + 1) * KT) & (SPK - 1);   // last iter wraps: harmless dummy

        // (1) stage next K tile (in flight across the whole iteration)
        stageK(KBn, nkb);

        // (2) queue = [K(it) 4][V(it) 4][K(it+1) 4]; vmcnt(8) ==> K(it) landed
        //     (it=0: also covers prologue qf loads in every legal ordering)
        asm volatile("s_waitcnt vmcnt(8)" ::: "memory");
        __builtin_amdgcn_s_barrier();

        // (3) S partials = mfma(K, Q) over this wave's ch-half; each kf read
        //     feeds BOTH query sub-groups -> 4 independent 8-deep chains
        const char* kE = KBc + BK;
        const char* kO = KBc + (BK ^ 64);
        f32x4 Sa0 = {0.f,0.f,0.f,0.f}, Sb0 = {0.f,0.f,0.f,0.f};
        f32x4 Sa1 = {0.f,0.f,0.f,0.f}, Sb1 = {0.f,0.f,0.f,0.f};
        __builtin_amdgcn_s_setprio(1);
        #pragma unroll
        for (int kt = 0; kt < 8; kt++) {
            const char* p = (kt & 1) ? kO : kE;
            bf16x8 k0 = *(const bf16x8*)(p + (kt >> 1) * 128);
            bf16x8 k1 = *(const bf16x8*)(p + (kt >> 1) * 128 + 16384);
            Sa0 = __builtin_amdgcn_mfma_f32_16x16x32_bf16(k0, qf0[kt], Sa0, 0, 0, 0);
            Sb0 = __builtin_amdgcn_mfma_f32_16x16x32_bf16(k1, qf0[kt], Sb0, 0, 0, 0);
            Sa1 = __builtin_amdgcn_mfma_f32_16x16x32_bf16(k0, qf1[kt], Sa1, 0, 0, 0);
            Sb1 = __builtin_amdgcn_mfma_f32_16x16x32_bf16(k1, qf1[kt], Sb1, 0, 0, 0);
        }
        __builtin_amdgcn_s_setprio(0);

        // (4) exchange partials with cs-partner; vmcnt(4) also gates V(it)
        *(f32x4*)(SX + sxw)                = Sa0;
        *(f32x4*)(SX + (sxw ^ 16))         = Sb0;
        *(f32x4*)(SX + sxw + 128)          = Sa1;
        *(f32x4*)(SX + ((sxw + 128) ^ 16)) = Sb1;
        asm volatile("s_waitcnt vmcnt(4) lgkmcnt(0)" ::: "memory");
        __builtin_amdgcn_s_barrier();
        Sa0 += *(const f32x4*)(SX + sxr);
        Sb0 += *(const f32x4*)(SX + (sxr ^ 16));
        Sa1 += *(const f32x4*)(SX + sxr + 128);
        Sb1 += *(const f32x4*)(SX + ((sxr + 128) ^ 16));

        // (5) in-register online softmax per qt (defer-max THR=8, shared branch)
        float mx0 = fmaxf(fmaxf(fmaxf(Sa0[0],Sa0[1]), fmaxf(Sa0[2],Sa0[3])),
                          fmaxf(fmaxf(Sb0[0],Sb0[1]), fmaxf(Sb0[2],Sb0[3])));
        float mx1 = fmaxf(fmaxf(fmaxf(Sa1[0],Sa1[1]), fmaxf(Sa1[2],Sa1[3])),
                          fmaxf(fmaxf(Sb1[0],Sb1[1]), fmaxf(Sb1[2],Sb1[3])));
        mx0 = fmaxf(mx0, __shfl_xor(mx0, 16, 64));
        mx0 = fmaxf(mx0, __shfl_xor(mx0, 32, 64));
        mx1 = fmaxf(mx1, __shfl_xor(mx1, 16, 64));
        mx1 = fmaxf(mx1, __shfl_xor(mx1, 32, 64));
        if (!__all((mx0 <= m0_reg + 8.f) && (mx1 <= m1_reg + 8.f))) {
            float mn0 = fmaxf(m0_reg, mx0), al0 = __expf(m0_reg - mn0);
            float mn1 = fmaxf(m1_reg, mx1), al1 = __expf(m1_reg - mn1);
            l0_reg *= al0; l1_reg *= al1;
            #pragma unroll
            for (int ct = 0; ct < 16; ct++) {
                #pragma unroll
                for (int r = 0; r < 4; r++) { O0[ct][r] *= al0; O1[ct][r] *= al1; }
            }
            m0_reg = mn0; m1_reg = mn1;
        }
        float e00 = __expf(Sa0[0]-m0_reg), e01 = __expf(Sa0[1]-m0_reg);
        float e02 = __expf(Sa0[2]-m0_reg), e03 = __expf(Sa0[3]-m0_reg);
        float e04 = __expf(Sb0[0]-m0_reg), e05 = __expf(Sb0[1]-m0_reg);
        float e06 = __expf(Sb0[2]-m0_reg), e07 = __expf(Sb0[3]-m0_reg);
        float e10 = __expf(Sa1[0]-m1_reg), e11 = __expf(Sa1[1]-m1_reg);
        float e12 = __expf(Sa1[2]-m1_reg), e13 = __expf(Sa1[3]-m1_reg);
        float e14 = __expf(Sb1[0]-m1_reg), e15 = __expf(Sb1[1]-m1_reg);
        float e16 = __expf(Sb1[2]-m1_reg), e17 = __expf(Sb1[3]-m1_reg);
        float ts0 = ((e00+e01)+(e02+e03)) + ((e04+e05)+(e06+e07));
        float ts1 = ((e10+e11)+(e12+e13)) + ((e14+e15)+(e16+e17));
        ts0 += __shfl_xor(ts0, 16, 64);
        ts0 += __shfl_xor(ts0, 32, 64);
        ts1 += __shfl_xor(ts1, 16, 64);
        ts1 += __shfl_xor(ts1, 32, 64);
        l0_reg += ts0; l1_reg += ts1;
        bf16x8 pf0, pf1;
        pf0[0] = f2b(e00); pf0[1] = f2b(e01); pf0[2] = f2b(e02); pf0[3] = f2b(e03);
        pf0[4] = f2b(e04); pf0[5] = f2b(e05); pf0[6] = f2b(e06); pf0[7] = f2b(e07);
        pf1[0] = f2b(e10); pf1[1] = f2b(e11); pf1[2] = f2b(e12); pf1[3] = f2b(e13);
        pf1[4] = f2b(e14); pf1[5] = f2b(e15); pf1[6] = f2b(e16); pf1[7] = f2b(e17);

        // (6) PV: each vf read feeds BOTH query sub-groups
        const char* vp = VB + BV;
        __builtin_amdgcn_s_setprio(1);
        #pragma unroll
        for (int ct = 0; ct < 16; ct++) {
            bf16x8 vv = *(const bf16x8*)(vp + ct * 1024);
            O0[ct] = __builtin_amdgcn_mfma_f32_16x16x32_bf16(vv, pf0, O0[ct], 0, 0, 0);
            O1[ct] = __builtin_amdgcn_mfma_f32_16x16x32_bf16(vv, pf1, O1[ct], 0, 0, 0);
        }
        __builtin_amdgcn_s_setprio(0);

        // (7) all waves' V/SX reads done -> safe to overwrite VB
        asm volatile("s_waitcnt lgkmcnt(0)" ::: "memory");
        __builtin_amdgcn_s_barrier();

        // (8) stage next V tile into the single buffer
        stageV(nkb);
    }
    asm volatile("s_waitcnt vmcnt(0)" ::: "memory");   // drain dummy stages before exit

    // ---- store partial O numerators + m,l (both query sub-groups)
    size_t n0 = (size_t)(b * NSP + sp) * NPIX + q0 + qg * 32 + ln;
    size_t n1 = n0 + 16;
    unsigned short* Ob0 = Opart + n0 * CH + cs * 256 + quad * 4;
    unsigned short* Ob1 = Opart + n1 * CH + cs * 256 + quad * 4;
    #pragma unroll
    for (int ct = 0; ct < 16; ct++) {
        bf16x4 pk0, pk1;
        #pragma unroll
        for (int r = 0; r < 4; r++) { pk0[r] = f2b(O0[ct][r]); pk1[r] = f2b(O1[ct][r]); }
        *(bf16x4*)(Ob0 + ct * 16) = pk0;
        *(bf16x4*)(Ob1 + ct * 16) = pk1;
    }
    if (cs == 0 && quad == 0) {
        ml[n0 * 2 + 0] = m0_reg;
        ml[n0 * 2 + 1] = l0_reg;
        ml[n1 * 2 + 0] = m1_reg;
        ml[n1 * 2 + 1] = l1_reg;
    }
}

// ---------------------------------------------------------------- merge 4 splits + proj + residual
__global__ __launch_bounds__(512, 2) void merge_kernel(
    const float* __restrict__ x,
    const unsigned short* __restrict__ Opart,
    const float* __restrict__ ml,
    const unsigned short* __restrict__ pw,   // bf16 proj_w [512][512]
    const float* __restrict__ pb,
    float* __restrict__ out)
{
    __shared__ __align__(16) unsigned short ao[32][520];
    int b  = blockIdx.y;
    int q0 = blockIdx.x * 32;
    int tid = threadIdx.x;
    int wv = tid >> 6, lane = tid & 63, ln = lane & 15, quad = lane >> 4;

    {   // combine splits: p = tid&31 (pixel), cs = tid>>5 (16 slots of 8ch)
        int p = tid & 31, cs = tid >> 5;
        int n = q0 + p;
        float m[NSP], l[NSP];
        #pragma unroll
        for (int s = 0; s < NSP; s++) {
            size_t i = ((size_t)(b * NSP + s) * NPIX + n) * 2;
            m[s] = ml[i]; l[s] = ml[i + 1];
        }
        float M = fmaxf(fmaxf(m[0], m[1]), fmaxf(m[2], m[3]));
        float w[NSP]; float den = 0.f;
        #pragma unroll
        for (int s = 0; s < NSP; s++) { w[s] = __expf(m[s] - M); den += l[s] * w[s]; }
        float dinv = 1.f / den;
        #pragma unroll
        for (int s = 0; s < NSP; s++) w[s] *= dinv;
        #pragma unroll
        for (int k = 0; k < 4; k++) {
            int c = cs * 8 + k * 128;
            float acc8[8] = {0.f,0.f,0.f,0.f,0.f,0.f,0.f,0.f};
            #pragma unroll
            for (int s = 0; s < NSP; s++) {
                const unsigned short* Os = Opart + ((size_t)(b * NSP + s) * NPIX + n) * CH;
                bf16x8 a = *(const bf16x8*)(Os + c);
                #pragma unroll
                for (int j = 0; j < 8; j++) acc8[j] += b2f((unsigned short)a[j]) * w[s];
            }
            #pragma unroll
            for (int j = 0; j < 8; j++) ao[p][c + j] = f2b(acc8[j]);
        }
    }
    __syncthreads();

    // ---- proj: out channels [wv*64,+64) + bias + residual (fp32)
    #pragma unroll
    for (int nt = 0; nt < 4; nt++) {
        int o = wv * 64 + nt * 16 + ln;
        const unsigned short* bp = pw + (size_t)o * CH + quad * 8;
        bf16x8 wf[16];
        #pragma unroll
        for (int k = 0; k < 16; k++) wf[k] = *(const bf16x8*)(bp + k * 32);
        float bi = pb[o];
        #pragma unroll
        for (int qt = 0; qt < 2; qt++) {
            f32x4 acc = {0.f, 0.f, 0.f, 0.f};
            #pragma unroll
            for (int k = 0; k < 16; k++) {
                bf16x8 a = *(const bf16x8*)(&ao[qt * 16 + ln][quad * 8 + k * 32]);
                acc = __builtin_amdgcn_mfma_f32_16x16x32_bf16(a, wf[k], acc, 0, 0, 0);
            }
            size_t base = ((size_t)b * CH + o) * NPIX + q0 + qt * 16 + quad * 4;
            f32x4 xin = *(const f32x4*)(x + base);
            f32x4 o4;
            #pragma unroll
            for (int r = 0; r < 4; r++) o4[r] = xin[r] + acc[r] + bi;
            *(f32x4*)(out + base) = o4;
        }
    }
}

// ----------------------------------------------------------------
extern "C" void kernel_launch(void* const* d_in, const int* in_sizes, int n_in,
                              void* d_out, int out_size, void* d_ws, size_t ws_size,
                              hipStream_t stream)
{
    const float* x      = (const float*)d_in[0];
    const float* gn_g   = (const float*)d_in[1];
    const float* gn_b   = (const float*)d_in[2];
    const float* qkv_w  = (const float*)d_in[3];
    const float* qkv_b  = (const float*)d_in[4];
    const float* proj_w = (const float*)d_in[5];
    const float* proj_b = (const float*)d_in[6];
    float* out = (float*)d_out;

    // Workspace (shorts): K 4M | V 4M | Q 4M | wbf 1M | stats/part/ml | Opart 16M (~58.5MB)
    unsigned short* ws  = (unsigned short*)d_ws;
    unsigned short* Kb  = ws;                           // [2][4096][512]
    unsigned short* Vb  = ws + 4u * 1024 * 1024;        // [2][512][4096] (pi-permuted groups)
    unsigned short* Qb  = ws + 8u * 1024 * 1024;        // [2][4096][512] (scaled)
    unsigned short* wbf = ws + 12u * 1024 * 1024;       // qkv_w | proj_w bf16
    unsigned short* wp  = wbf + 786432;
    float* stats = (float*)(ws + 13u * 1024 * 1024);             // 128 f32
    f32x2* part  = (f32x2*)(ws + 13u * 1024 * 1024 + 1024);      // 256 f32x2
    float* ml    = (float*)(ws + 13u * 1024 * 1024 + 4096);      // [2][4][4096][2] f32
    unsigned short* Opart = ws + 13u * 1024 * 1024 + 4096 + 262144;

    convert_kernel<<<dim3(1048576 / 256), 256, 0, stream>>>(qkv_w, proj_w, wbf);
    stats1_kernel <<<dim3(256), 256, 0, stream>>>(x, part);
    stats2_kernel <<<dim3(1), 64, 0, stream>>>(part, stats);
    qkv_kernel    <<<dim3(NPIX / 64, BATCH, 3), 256, 0, stream>>>(
        x, wbf, qkv_b, gn_g, gn_b, stats, Qb, Kb, Vb);
    attn_kernel   <<<dim3(256), 512, 0, stream>>>(Qb, Kb, Vb, Opart, ml);
    merge_kernel  <<<dim3(NPIX / 32, BATCH), 512, 0, stream>>>(
        x, Opart, ml, wp, proj_b, out);
}

// Round 11
// 337.827 us; speedup vs baseline: 1.1906x; 1.1312x over previous
//
#include <hip/hip_runtime.h>

typedef __attribute__((ext_vector_type(8))) short bf16x8;
typedef __attribute__((ext_vector_type(4))) short bf16x4;
typedef __attribute__((ext_vector_type(4))) float f32x4;
typedef __attribute__((ext_vector_type(2))) float f32x2;

#define BATCH 2
#define CH    512
#define NPIX  4096
#define NSP   2
#define SPK   2048   // keys per split
#define KT    32     // keys per tile

__device__ __forceinline__ unsigned short f2b(float f) {
    unsigned int u; __builtin_memcpy(&u, &f, 4);
    u = u + 0x7FFFu + ((u >> 16) & 1u);   // RNE
    return (unsigned short)(u >> 16);
}
__device__ __forceinline__ float b2f(unsigned short h) {
    unsigned int u = ((unsigned int)h) << 16;
    float f; __builtin_memcpy(&f, &u, 4);
    return f;
}
// async 16B/lane global->LDS (wave-uniform LDS base, per-lane global src)
__device__ __forceinline__ void gll16(void* lds, const void* g) {
    __builtin_amdgcn_global_load_lds(
        (const __attribute__((address_space(1))) void*)g,
        (__attribute__((address_space(3))) void*)lds, 16, 0, 0);
}

// ---------------------------------------------------------------- fp32 -> bf16 weight convert
// Fragment-major layout: 16B chunk idx = ((rg*16 + k)*4 + quad)*16 + rr
// (rg=row>>4, rr=row&15, k=c>>5, quad=(c>>3)&3, elem=c&7) -> a wave's wf[k]
// load (lanes = quad*16+rr) is one contiguous 1KB segment (fully coalesced).
__global__ __launch_bounds__(256) void convert_kernel(
    const float* __restrict__ qkv_w, const float* __restrict__ proj_w,
    unsigned short* __restrict__ wbf)
{
    int i = blockIdx.x * 256 + threadIdx.x;            // grid covers 1048576
    float v; int row, c; unsigned short* ob;
    if (i < 786432) { v = qkv_w[i];          row = i >> 9;  c = i & 511; ob = wbf; }
    else            { int j = i - 786432; v = proj_w[j]; row = j >> 9; c = j & 511; ob = wbf + 786432; }
    size_t o = ((size_t)((((row >> 4) * 16 + (c >> 5)) * 4 + ((c >> 3) & 3)) * 16 + (row & 15))) * 8 + (c & 7);
    ob[o] = f2b(v);
}

// ---------------------------------------------------------------- GN stats (2-stage, parallel)
__global__ __launch_bounds__(256) void stats1_kernel(
    const float* __restrict__ x, f32x2* __restrict__ part)
{
    int id = blockIdx.x;            // 256 blocks: bg*4 + quarter
    int bg = id >> 2, q = id & 3;
    int b = bg >> 5, g = bg & 31;
    const float* xp = x + ((size_t)b * CH + (size_t)g * 16 + q * 4) * NPIX;
    float s = 0.f, ss = 0.f;
    for (int i = threadIdx.x; i < 4 * NPIX; i += 256) {
        float v = xp[i]; s += v; ss += v * v;
    }
    for (int off = 32; off; off >>= 1) {
        s  += __shfl_down(s,  off, 64);
        ss += __shfl_down(ss, off, 64);
    }
    __shared__ float red[2][4];
    int wv = threadIdx.x >> 6;
    if ((threadIdx.x & 63) == 0) { red[0][wv] = s; red[1][wv] = ss; }
    __syncthreads();
    if (threadIdx.x == 0) {
        s  = red[0][0] + red[0][1] + red[0][2] + red[0][3];
        ss = red[1][0] + red[1][1] + red[1][2] + red[1][3];
        part[id] = (f32x2){s, ss};
    }
}

__global__ __launch_bounds__(64) void stats2_kernel(
    const f32x2* __restrict__ part, float* __restrict__ stats)
{
    int t = threadIdx.x;            // 64 = b*32+g
    float s = 0.f, ss = 0.f;
    #pragma unroll
    for (int q = 0; q < 4; q++) { f32x2 p = part[t * 4 + q]; s += p[0]; ss += p[1]; }
    const float inv = 1.f / (16 * NPIX);
    float mean = s * inv;
    float var  = ss * inv - mean * mean;
    stats[t * 2 + 0] = mean;
    stats[t * 2 + 1] = rsqrtf(var + 1e-6f);
}

// ---------------------------------------------------------------- Q/K/V GEMM + fused GroupNorm
// grid (64, 2, 3) = 384 blocks, 2 blocks/CU. third 0->Q (scaled), 1->K, 2->V.
// Weights read via the fragment-major layout (coalesced 1KB/wave/fragment).
// V stored PI-PERMUTED within each 32-key group (round-7-verified layout).
__global__ __launch_bounds__(256, 2) void qkv_kernel(
    const float* __restrict__ x,
    const unsigned short* __restrict__ wbf,  // bf16 qkv_w, fragment-major
    const float* __restrict__ bias,
    const float* __restrict__ gamma,
    const float* __restrict__ beta,
    const float* __restrict__ stats,
    unsigned short* __restrict__ Q,          // [b][n][c] pre-scaled
    unsigned short* __restrict__ K,          // [b][n][c]
    unsigned short* __restrict__ V)          // [b][c][grp][32 permuted]
{
    __shared__ unsigned short hn[64][520];
    int b     = blockIdx.y;
    int third = blockIdx.z;
    int m0    = blockIdx.x * 64;
    int tid = threadIdx.x;
    {   // stage + normalize: p4 = (tid&15)*4 (4 pixels), cg = tid>>4 (16 ch slots)
        const float* xb = x + (size_t)b * CH * NPIX + m0;
        const float* st = stats + b * 64;
        int p4 = (tid & 15) * 4, cg = tid >> 4;
        for (int c0 = 0; c0 < CH; c0 += 16) {
            int c = c0 + cg;
            float mean = st[(c >> 4) * 2 + 0];
            float rstd = st[(c >> 4) * 2 + 1];
            float ga = gamma[c] * rstd;
            float be = beta[c] - mean * ga;
            f32x4 v = *(const f32x4*)(xb + (size_t)c * NPIX + p4);
            hn[p4 + 0][c] = f2b(v[0] * ga + be);
            hn[p4 + 1][c] = f2b(v[1] * ga + be);
            hn[p4 + 2][c] = f2b(v[2] * ga + be);
            hn[p4 + 3][c] = f2b(v[3] * ga + be);
        }
    }
    __syncthreads();

    int wv = tid >> 6, lane = tid & 63, ln = lane & 15, quad = lane >> 4;
    const float scale = 0.04419417382415922f;  // 512^-0.5
    #pragma unroll
    for (int nt = 0; nt < 8; nt++) {
        int o = nt * 64 + wv * 16 + ln;            // [0, 512)
        int row = third * 512 + o;
        int rg  = third * 32 + nt * 4 + wv;        // row-group (row0 >> 4)
        const unsigned short* bp = wbf + (size_t)rg * 8192 + quad * 128 + ln * 8;
        bf16x8 wf[16];
        #pragma unroll
        for (int k = 0; k < 16; k++) wf[k] = *(const bf16x8*)(bp + k * 512);
        float bi = bias[row];
        #pragma unroll
        for (int qt = 0; qt < 4; qt++) {
            f32x4 acc = {0.f, 0.f, 0.f, 0.f};
            #pragma unroll
            for (int k = 0; k < 16; k++) {
                bf16x8 a = *(const bf16x8*)(&hn[qt * 16 + ln][quad * 8 + k * 32]);
                acc = __builtin_amdgcn_mfma_f32_16x16x32_bf16(a, wf[k], acc, 0, 0, 0);
            }
            int m = m0 + qt * 16 + quad * 4;
            if (third == 0) {
                #pragma unroll
                for (int r = 0; r < 4; r++)
                    Q[((size_t)b * NPIX + m + r) * CH + o] = f2b((acc[r] + bi) * scale);
            } else if (third == 1) {
                #pragma unroll
                for (int r = 0; r < 4; r++)
                    K[((size_t)b * NPIX + m + r) * CH + o] = f2b(acc[r] + bi);
            } else {
                bf16x4 pk;
                #pragma unroll
                for (int r = 0; r < 4; r++) pk[r] = f2b(acc[r] + bi);
                int grp = m & ~31;
                int s   = ((m & 15) >> 2) * 8 + ((m >> 4) & 1) * 4;  // pi position
                *(bf16x4*)(V + ((size_t)b * CH + o) * NPIX + grp + s) = pk;
            }
        }
    }
}

// ---------------------------------------------------------------- attention: in-register flash
// (round-7 kernel verbatim — proven 144 us)
__global__ __launch_bounds__(512, 2) void attn_kernel(
    const unsigned short* __restrict__ Qg,   // [b][n][c] bf16, pre-scaled
    const unsigned short* __restrict__ Kg,   // [b][n][c]
    const unsigned short* __restrict__ Vg,   // [b][c][grp][32 perm]
    unsigned short* __restrict__ Opart,      // [b][sp][n][c] bf16 numerators
    float* __restrict__ ml)                  // [b][sp][n][2] f32
{
    // LDS 112KB: K dbuf 2x32K @0; V 32K @65536; SX 16K @98304.
    __shared__ __align__(16) char sm[114688];
    char* const KB0 = sm;
    char* const KB1 = sm + 32768;
    char* const VB  = sm + 65536;
    char* const SX  = sm + 98304;

    int bid = blockIdx.x;
    int xcd = bid & 7;
    int b  = (xcd >> 1) & 1;
    int sp = xcd & 1;
    int q0 = (((bid >> 3) << 1) | (xcd >> 2)) << 6;   // 64-query tiles
    int tid = threadIdx.x;
    int wv = tid >> 6, lane = tid & 63, ln = lane & 15, quad = lane >> 4;
    int qg = wv >> 1, cs = wv & 1;           // query group (16q), channel half (256c)

    const unsigned short* K = Kg + ((size_t)b * NPIX + (size_t)sp * SPK) * CH;
    const unsigned short* V = Vg + (size_t)b * CH * NPIX + (size_t)sp * SPK;
    const unsigned short* Qp = Qg + ((size_t)(b * NPIX + q0 + qg * 16)) * CH;

    auto stageK = [&](char* buf, int kb) {
        #pragma unroll
        for (int j = 0; j < 4; j++) {
            int r = wv * 4 + j;
            gll16(buf + r * 1024,
                  K + (size_t)(kb + r) * CH + ((lane ^ (r & 7)) << 3));
        }
    };
    auto stageV = [&](int kb) {
        #pragma unroll
        for (int j = 0; j < 4; j++) {
            int r0 = wv * 64 + j * 16;
            int ch = r0 + (lane >> 2);
            gll16(VB + r0 * 64,
                  V + (size_t)ch * NPIX + kb + (((lane & 3) ^ ((ch >> 1) & 3)) << 3));
        }
    };

    stageK(KB0, 0);
    bf16x8 qf[8];
    #pragma unroll
    for (int kt = 0; kt < 8; kt++)
        qf[kt] = *(const bf16x8*)(Qp + (size_t)ln * CH + cs * 256 + kt * 32 + quad * 8);
    stageV(0);

    const int BK = ln * 1024 + ((quad ^ (ln & 3)) << 4) + (((ln >> 2) & 1) << 6) + cs * 512;
    const int BV = (cs * 256 + ln) * 64 + ((quad ^ ((ln >> 1) & 3)) << 4);
    const int sxo = ((quad ^ (ln & 3)) << 5) + (((ln >> 2) & 1) << 4);
    const int sxw = ((wv * 16 + ln) << 7) + sxo;
    const int sxr = (((wv ^ 1) * 16 + ln) << 7) + sxo;

    f32x4 O[16];
    #pragma unroll
    for (int i = 0; i < 16; i++) O[i] = (f32x4){0.f, 0.f, 0.f, 0.f};
    float m_reg = -1e30f, l_reg = 0.f;

    for (int it = 0; it < SPK / KT; ++it) {
        char* const KBc = (it & 1) ? KB1 : KB0;
        char* const KBn = (it & 1) ? KB0 : KB1;
        int nkb = ((it + 1) * KT) & (SPK - 1);

        stageK(KBn, nkb);

        asm volatile("s_waitcnt vmcnt(8)" ::: "memory");
        __builtin_amdgcn_s_barrier();

        const char* kE = KBc + BK;
        const char* kO = KBc + (BK ^ 64);
        f32x4 Sa = {0.f,0.f,0.f,0.f}, Sb = {0.f,0.f,0.f,0.f};
        __builtin_amdgcn_s_setprio(1);
        #pragma unroll
        for (int kt = 0; kt < 8; kt++) {
            const char* p = (kt & 1) ? kO : kE;
            bf16x8 k0 = *(const bf16x8*)(p + (kt >> 1) * 128);
            bf16x8 k1 = *(const bf16x8*)(p + (kt >> 1) * 128 + 16384);
            Sa = __builtin_amdgcn_mfma_f32_16x16x32_bf16(k0, qf[kt], Sa, 0, 0, 0);
            Sb = __builtin_amdgcn_mfma_f32_16x16x32_bf16(k1, qf[kt], Sb, 0, 0, 0);
        }
        __builtin_amdgcn_s_setprio(0);

        *(f32x4*)(SX + sxw)        = Sa;
        *(f32x4*)(SX + (sxw ^ 16)) = Sb;
        asm volatile("s_waitcnt vmcnt(4) lgkmcnt(0)" ::: "memory");
        __builtin_amdgcn_s_barrier();
        Sa += *(const f32x4*)(SX + sxr);
        Sb += *(const f32x4*)(SX + (sxr ^ 16));

        float mx = fmaxf(fmaxf(fmaxf(Sa[0],Sa[1]), fmaxf(Sa[2],Sa[3])),
                         fmaxf(fmaxf(Sb[0],Sb[1]), fmaxf(Sb[2],Sb[3])));
        mx = fmaxf(mx, __shfl_xor(mx, 16, 64));
        mx = fmaxf(mx, __shfl_xor(mx, 32, 64));
        if (!__all(mx <= m_reg + 8.f)) {
            float mnew  = fmaxf(m_reg, mx);
            float alpha = __expf(m_reg - mnew);
            l_reg *= alpha;
            #pragma unroll
            for (int ct = 0; ct < 16; ct++) {
                #pragma unroll
                for (int r = 0; r < 4; r++) O[ct][r] *= alpha;
            }
            m_reg = mnew;
        }
        float e0 = __expf(Sa[0]-m_reg), e1 = __expf(Sa[1]-m_reg);
        float e2 = __expf(Sa[2]-m_reg), e3 = __expf(Sa[3]-m_reg);
        float e4 = __expf(Sb[0]-m_reg), e5 = __expf(Sb[1]-m_reg);
        float e6 = __expf(Sb[2]-m_reg), e7 = __expf(Sb[3]-m_reg);
        float ts = ((e0+e1)+(e2+e3)) + ((e4+e5)+(e6+e7));
        ts += __shfl_xor(ts, 16, 64);
        ts += __shfl_xor(ts, 32, 64);
        l_reg += ts;
        bf16x8 pf;
        pf[0] = f2b(e0); pf[1] = f2b(e1); pf[2] = f2b(e2); pf[3] = f2b(e3);
        pf[4] = f2b(e4); pf[5] = f2b(e5); pf[6] = f2b(e6); pf[7] = f2b(e7);

        const char* vp = VB + BV;
        __builtin_amdgcn_s_setprio(1);
        #pragma unroll
        for (int ct = 0; ct < 16; ct++) {
            bf16x8 vv = *(const bf16x8*)(vp + ct * 1024);
            O[ct] = __builtin_amdgcn_mfma_f32_16x16x32_bf16(vv, pf, O[ct], 0, 0, 0);
        }
        __builtin_amdgcn_s_setprio(0);

        asm volatile("s_waitcnt lgkmcnt(0)" ::: "memory");
        __builtin_amdgcn_s_barrier();

        stageV(nkb);
    }
    asm volatile("s_waitcnt vmcnt(0)" ::: "memory");

    size_t n = (size_t)(b * NSP + sp) * NPIX + q0 + qg * 16 + ln;
    unsigned short* Ob = Opart + n * CH + cs * 256 + quad * 4;
    #pragma unroll
    for (int ct = 0; ct < 16; ct++) {
        bf16x4 pk;
        #pragma unroll
        for (int r = 0; r < 4; r++) pk[r] = f2b(O[ct][r]);
        *(bf16x4*)(Ob + ct * 16) = pk;
    }
    if (cs == 0 && quad == 0) {
        ml[n * 2 + 0] = m_reg;
        ml[n * 2 + 1] = l_reg;
    }
}

// ---------------------------------------------------------------- merge 2 splits + proj + residual
// proj weights read via the fragment-major layout (coalesced).
__global__ __launch_bounds__(512, 2) void merge_kernel(
    const float* __restrict__ x,
    const unsigned short* __restrict__ Opart,
    const float* __restrict__ ml,
    const unsigned short* __restrict__ pw,   // bf16 proj_w, fragment-major
    const float* __restrict__ pb,
    float* __restrict__ out)
{
    __shared__ __align__(16) unsigned short ao[32][520];
    int b  = blockIdx.y;
    int q0 = blockIdx.x * 32;
    int tid = threadIdx.x;
    int wv = tid >> 6, lane = tid & 63, ln = lane & 15, quad = lane >> 4;

    {   // combine splits: p = tid&31 (pixel), cs = tid>>5 (16 slots of 8ch)
        int p = tid & 31, cs = tid >> 5;
        int n = q0 + p;
        size_t i0 = ((size_t)(b * NSP + 0) * NPIX + n) * 2;
        size_t i1 = ((size_t)(b * NSP + 1) * NPIX + n) * 2;
        float m0 = ml[i0], l0 = ml[i0 + 1];
        float m1 = ml[i1], l1 = ml[i1 + 1];
        float M  = fmaxf(m0, m1);
        float e0 = __expf(m0 - M), e1 = __expf(m1 - M);
        float den = l0 * e0 + l1 * e1;
        float w0 = e0 / den, w1 = e1 / den;
        const unsigned short* O0 = Opart + ((size_t)(b * NSP + 0) * NPIX + n) * CH;
        const unsigned short* O1 = Opart + ((size_t)(b * NSP + 1) * NPIX + n) * CH;
        #pragma unroll
        for (int k = 0; k < 4; k++) {
            int c = cs * 8 + k * 128;
            bf16x8 a0 = *(const bf16x8*)(O0 + c);
            bf16x8 a1 = *(const bf16x8*)(O1 + c);
            #pragma unroll
            for (int j = 0; j < 8; j++)
                ao[p][c + j] = f2b(b2f((unsigned short)a0[j]) * w0 +
                                   b2f((unsigned short)a1[j]) * w1);
        }
    }
    __syncthreads();

    // ---- proj: out channels [wv*64,+64) + bias + residual (fp32)
    #pragma unroll
    for (int nt = 0; nt < 4; nt++) {
        int o = wv * 64 + nt * 16 + ln;
        int rg = wv * 4 + nt;                     // row-group
        const unsigned short* bp = pw + (size_t)rg * 8192 + quad * 128 + ln * 8;
        bf16x8 wf[16];
        #pragma unroll
        for (int k = 0; k < 16; k++) wf[k] = *(const bf16x8*)(bp + k * 512);
        float bi = pb[o];
        #pragma unroll
        for (int qt = 0; qt < 2; qt++) {
            f32x4 acc = {0.f, 0.f, 0.f, 0.f};
            #pragma unroll
            for (int k = 0; k < 16; k++) {
                bf16x8 a = *(const bf16x8*)(&ao[qt * 16 + ln][quad * 8 + k * 32]);
                acc = __builtin_amdgcn_mfma_f32_16x16x32_bf16(a, wf[k], acc, 0, 0, 0);
            }
            size_t base = ((size_t)b * CH + o) * NPIX + q0 + qt * 16 + quad * 4;
            f32x4 xin = *(const f32x4*)(x + base);
            f32x4 o4;
            #pragma unroll
            for (int r = 0; r < 4; r++) o4[r] = xin[r] + acc[r] + bi;
            *(f32x4*)(out + base) = o4;
        }
    }
}

// ----------------------------------------------------------------
extern "C" void kernel_launch(void* const* d_in, const int* in_sizes, int n_in,
                              void* d_out, int out_size, void* d_ws, size_t ws_size,
                              hipStream_t stream)
{
    const float* x      = (const float*)d_in[0];
    const float* gn_g   = (const float*)d_in[1];
    const float* gn_b   = (const float*)d_in[2];
    const float* qkv_w  = (const float*)d_in[3];
    const float* qkv_b  = (const float*)d_in[4];
    const float* proj_w = (const float*)d_in[5];
    const float* proj_b = (const float*)d_in[6];
    float* out = (float*)d_out;

    // Workspace (shorts): K 4M | V 4M | Q 4M | wbf 1M | stats/part/ml | Opart 8M (~42MB)
    unsigned short* ws  = (unsigned short*)d_ws;
    unsigned short* Kb  = ws;                           // [2][4096][512]
    unsigned short* Vb  = ws + 4u * 1024 * 1024;        // [2][512][4096] (pi-permuted groups)
    unsigned short* Qb  = ws + 8u * 1024 * 1024;        // [2][4096][512] (scaled)
    unsigned short* wbf = ws + 12u * 1024 * 1024;       // qkv_w | proj_w bf16 (fragment-major)
    unsigned short* wp  = wbf + 786432;
    float* stats = (float*)(ws + 13u * 1024 * 1024);             // 128 f32
    f32x2* part  = (f32x2*)(ws + 13u * 1024 * 1024 + 1024);      // 256 f32x2
    float* ml    = (float*)(ws + 13u * 1024 * 1024 + 4096);      // [2][2][4096][2] f32
    unsigned short* Opart = ws + 13u * 1024 * 1024 + 4096 + 131072;

    convert_kernel<<<dim3(1048576 / 256), 256, 0, stream>>>(qkv_w, proj_w, wbf);
    stats1_kernel <<<dim3(256), 256, 0, stream>>>(x, part);
    stats2_kernel <<<dim3(1), 64, 0, stream>>>(part, stats);
    qkv_kernel    <<<dim3(NPIX / 64, BATCH, 3), 256, 0, stream>>>(
        x, wbf, qkv_b, gn_g, gn_b, stats, Qb, Kb, Vb);
    attn_kernel   <<<dim3(256), 512, 0, stream>>>(Qb, Kb, Vb, Opart, ml);
    merge_kernel  <<<dim3(NPIX / 32, BATCH), 512, 0, stream>>>(
        x, Opart, ml, wp, proj_b, out);
}

// Round 12
// 271.352 us; speedup vs baseline: 1.4823x; 1.2450x over previous
//
#include <hip/hip_runtime.h>

typedef __attribute__((ext_vector_type(8))) short bf16x8;
typedef __attribute__((ext_vector_type(4))) short bf16x4;
typedef __attribute__((ext_vector_type(4))) float f32x4;
typedef __attribute__((ext_vector_type(2))) float f32x2;

#define BATCH 2
#define CH    512
#define NPIX  4096
#define NSP   2
#define SPK   2048   // keys per split
#define KT    32     // keys per tile

__device__ __forceinline__ unsigned short f2b(float f) {
    unsigned int u; __builtin_memcpy(&u, &f, 4);
    u = u + 0x7FFFu + ((u >> 16) & 1u);   // RNE
    return (unsigned short)(u >> 16);
}
__device__ __forceinline__ float b2f(unsigned short h) {
    unsigned int u = ((unsigned int)h) << 16;
    float f; __builtin_memcpy(&f, &u, 4);
    return f;
}
// async 16B/lane global->LDS (wave-uniform LDS base, per-lane global src)
__device__ __forceinline__ void gll16(void* lds, const void* g) {
    __builtin_amdgcn_global_load_lds(
        (const __attribute__((address_space(1))) void*)g,
        (__attribute__((address_space(3))) void*)lds, 16, 0, 0);
}

// ---------------------------------------------------------------- convert + GN stats stage1 (fused)
// blocks [0,4096): fp32->bf16 weight convert into fragment-major layout:
//   chunk idx = ((rg*16 + k)*4 + quad)*16 + rr  (rg=row>>4, rr=row&15,
//   k=c>>5, quad=(c>>3)&3, elem=c&7) -> wf[k] load = contiguous 1KB/wave.
// blocks [4096,4352): GN stats partial sums (bg*4+quarter).
__global__ __launch_bounds__(256) void convstats_kernel(
    const float* __restrict__ qkv_w, const float* __restrict__ proj_w,
    const float* __restrict__ x,
    unsigned short* __restrict__ wbf, f32x2* __restrict__ part)
{
    if (blockIdx.x < 4096) {
        int i = blockIdx.x * 256 + threadIdx.x;            // covers 1048576
        float v; int row, c; unsigned short* ob;
        if (i < 786432) { v = qkv_w[i];       row = i >> 9; c = i & 511; ob = wbf; }
        else            { int j = i - 786432; v = proj_w[j]; row = j >> 9; c = j & 511; ob = wbf + 786432; }
        size_t o = ((size_t)((((row >> 4) * 16 + (c >> 5)) * 4 + ((c >> 3) & 3)) * 16 + (row & 15))) * 8 + (c & 7);
        ob[o] = f2b(v);
        return;
    }
    int id = blockIdx.x - 4096;     // 256 blocks: bg*4 + quarter
    int bg = id >> 2, q = id & 3;
    int b = bg >> 5, g = bg & 31;
    const float* xp = x + ((size_t)b * CH + (size_t)g * 16 + q * 4) * NPIX;
    float s = 0.f, ss = 0.f;
    for (int i = threadIdx.x; i < 4 * NPIX; i += 256) {
        float v = xp[i]; s += v; ss += v * v;
    }
    for (int off = 32; off; off >>= 1) {
        s  += __shfl_down(s,  off, 64);
        ss += __shfl_down(ss, off, 64);
    }
    __shared__ float red[2][4];
    int wv = threadIdx.x >> 6;
    if ((threadIdx.x & 63) == 0) { red[0][wv] = s; red[1][wv] = ss; }
    __syncthreads();
    if (threadIdx.x == 0) {
        s  = red[0][0] + red[0][1] + red[0][2] + red[0][3];
        ss = red[1][0] + red[1][1] + red[1][2] + red[1][3];
        part[id] = (f32x2){s, ss};
    }
}

// ---------------------------------------------------------------- Q/K/V GEMM + fused GroupNorm
// grid (64, 2, 3) = 384 blocks, 2 blocks/CU. third 0->Q (scaled), 1->K, 2->V.
// Group stats re-reduced per block from part[] (no stats2 kernel).
// Thirds 0/1 use FLIPPED operand order mfma(wf, hn): D[row=o][col=pixel] ->
// store = one bf16x4 (4 consecutive channels) per fragment, 4x fewer store
// instructions. wf per-lane data is IDENTICAL for A- and B-roles, so the same
// fragment-major weight layout serves both. V third keeps mfma(hn, wf)
// (pixel-consecutive) + pi-permuted [c][grp][32] layout (round-7-verified).
__global__ __launch_bounds__(256, 2) void qkv_kernel(
    const float* __restrict__ x,
    const unsigned short* __restrict__ wbf,  // bf16 qkv_w, fragment-major
    const float* __restrict__ bias,
    const float* __restrict__ gamma,
    const float* __restrict__ beta,
    const f32x2* __restrict__ part,
    unsigned short* __restrict__ Q,          // [b][n][c] pre-scaled
    unsigned short* __restrict__ K,          // [b][n][c]
    unsigned short* __restrict__ V)          // [b][c][grp][32 permuted]
{
    __shared__ unsigned short hn[64][520];
    __shared__ float st2[32][2];
    int b     = blockIdx.y;
    int third = blockIdx.z;
    int m0    = blockIdx.x * 64;
    int tid = threadIdx.x;

    if (tid < 32) {   // re-reduce group stats for this batch
        float s = 0.f, ss = 0.f;
        #pragma unroll
        for (int q = 0; q < 4; q++) {
            f32x2 p = part[(b * 32 + tid) * 4 + q];
            s += p[0]; ss += p[1];
        }
        const float inv = 1.f / (16 * NPIX);
        float mean = s * inv;
        float var  = ss * inv - mean * mean;
        st2[tid][0] = mean;
        st2[tid][1] = rsqrtf(var + 1e-6f);
    }
    __syncthreads();

    {   // stage + normalize: p4 = (tid&15)*4 (4 pixels), cg = tid>>4 (16 ch slots)
        const float* xb = x + (size_t)b * CH * NPIX + m0;
        int p4 = (tid & 15) * 4, cg = tid >> 4;
        for (int c0 = 0; c0 < CH; c0 += 16) {
            int c = c0 + cg;
            float mean = st2[c >> 4][0];
            float rstd = st2[c >> 4][1];
            float ga = gamma[c] * rstd;
            float be = beta[c] - mean * ga;
            f32x4 v = *(const f32x4*)(xb + (size_t)c * NPIX + p4);
            hn[p4 + 0][c] = f2b(v[0] * ga + be);
            hn[p4 + 1][c] = f2b(v[1] * ga + be);
            hn[p4 + 2][c] = f2b(v[2] * ga + be);
            hn[p4 + 3][c] = f2b(v[3] * ga + be);
        }
    }
    __syncthreads();

    int wv = tid >> 6, lane = tid & 63, ln = lane & 15, quad = lane >> 4;
    const float scale = 0.04419417382415922f;  // 512^-0.5
    #pragma unroll
    for (int nt = 0; nt < 8; nt++) {
        int obase = nt * 64 + wv * 16;
        int rg    = third * 32 + nt * 4 + wv;      // row-group (o0 >> 4)
        const unsigned short* bp = wbf + (size_t)rg * 8192 + quad * 128 + ln * 8;
        bf16x8 wf[16];
        #pragma unroll
        for (int k = 0; k < 16; k++) wf[k] = *(const bf16x8*)(bp + k * 512);

        if (third == 2) {
            // V: D[row=pixel][col=o]; store 4 consecutive pixels at channel o
            float bi = bias[1024 + obase + ln];
            #pragma unroll
            for (int qt = 0; qt < 4; qt++) {
                f32x4 acc = {0.f, 0.f, 0.f, 0.f};
                #pragma unroll
                for (int k = 0; k < 16; k++) {
                    bf16x8 a = *(const bf16x8*)(&hn[qt * 16 + ln][quad * 8 + k * 32]);
                    acc = __builtin_amdgcn_mfma_f32_16x16x32_bf16(a, wf[k], acc, 0, 0, 0);
                }
                int m = m0 + qt * 16 + quad * 4;
                bf16x4 pk;
                #pragma unroll
                for (int r = 0; r < 4; r++) pk[r] = f2b(acc[r] + bi);
                int grp = m & ~31;
                int s   = ((m & 15) >> 2) * 8 + ((m >> 4) & 1) * 4;  // pi position
                *(bf16x4*)(V + ((size_t)b * CH + obase + ln) * NPIX + grp + s) = pk;
            }
        } else {
            // Q/K flipped: D[row=o][col=pixel]; store 4 consecutive channels
            f32x4 bi4 = *(const f32x4*)(bias + third * 512 + obase + quad * 4);
            unsigned short* dst = (third == 0) ? Q : K;
            #pragma unroll
            for (int qt = 0; qt < 4; qt++) {
                f32x4 acc = {0.f, 0.f, 0.f, 0.f};
                #pragma unroll
                for (int k = 0; k < 16; k++) {
                    bf16x8 a = *(const bf16x8*)(&hn[qt * 16 + ln][quad * 8 + k * 32]);
                    acc = __builtin_amdgcn_mfma_f32_16x16x32_bf16(wf[k], a, acc, 0, 0, 0);
                }
                int n = m0 + qt * 16 + ln;
                bf16x4 pk;
                if (third == 0) {
                    #pragma unroll
                    for (int r = 0; r < 4; r++) pk[r] = f2b((acc[r] + bi4[r]) * scale);
                } else {
                    #pragma unroll
                    for (int r = 0; r < 4; r++) pk[r] = f2b(acc[r] + bi4[r]);
                }
                *(bf16x4*)(dst + ((size_t)b * NPIX + n) * CH + obase + quad * 4) = pk;
            }
        }
    }
}

// ---------------------------------------------------------------- attention: in-register flash
// (round-7 kernel verbatim — proven 144-146 us)
__global__ __launch_bounds__(512, 2) void attn_kernel(
    const unsigned short* __restrict__ Qg,   // [b][n][c] bf16, pre-scaled
    const unsigned short* __restrict__ Kg,   // [b][n][c]
    const unsigned short* __restrict__ Vg,   // [b][c][grp][32 perm]
    unsigned short* __restrict__ Opart,      // [b][sp][n][c] bf16 numerators
    float* __restrict__ ml)                  // [b][sp][n][2] f32
{
    // LDS 112KB: K dbuf 2x32K @0; V 32K @65536; SX 16K @98304.
    __shared__ __align__(16) char sm[114688];
    char* const KB0 = sm;
    char* const KB1 = sm + 32768;
    char* const VB  = sm + 65536;
    char* const SX  = sm + 98304;

    int bid = blockIdx.x;
    int xcd = bid & 7;
    int b  = (xcd >> 1) & 1;
    int sp = xcd & 1;
    int q0 = (((bid >> 3) << 1) | (xcd >> 2)) << 6;   // 64-query tiles
    int tid = threadIdx.x;
    int wv = tid >> 6, lane = tid & 63, ln = lane & 15, quad = lane >> 4;
    int qg = wv >> 1, cs = wv & 1;           // query group (16q), channel half (256c)

    const unsigned short* K = Kg + ((size_t)b * NPIX + (size_t)sp * SPK) * CH;
    const unsigned short* V = Vg + (size_t)b * CH * NPIX + (size_t)sp * SPK;
    const unsigned short* Qp = Qg + ((size_t)(b * NPIX + q0 + qg * 16)) * CH;

    auto stageK = [&](char* buf, int kb) {
        #pragma unroll
        for (int j = 0; j < 4; j++) {
            int r = wv * 4 + j;
            gll16(buf + r * 1024,
                  K + (size_t)(kb + r) * CH + ((lane ^ (r & 7)) << 3));
        }
    };
    auto stageV = [&](int kb) {
        #pragma unroll
        for (int j = 0; j < 4; j++) {
            int r0 = wv * 64 + j * 16;
            int ch = r0 + (lane >> 2);
            gll16(VB + r0 * 64,
                  V + (size_t)ch * NPIX + kb + (((lane & 3) ^ ((ch >> 1) & 3)) << 3));
        }
    };

    stageK(KB0, 0);
    bf16x8 qf[8];
    #pragma unroll
    for (int kt = 0; kt < 8; kt++)
        qf[kt] = *(const bf16x8*)(Qp + (size_t)ln * CH + cs * 256 + kt * 32 + quad * 8);
    stageV(0);

    const int BK = ln * 1024 + ((quad ^ (ln & 3)) << 4) + (((ln >> 2) & 1) << 6) + cs * 512;
    const int BV = (cs * 256 + ln) * 64 + ((quad ^ ((ln >> 1) & 3)) << 4);
    const int sxo = ((quad ^ (ln & 3)) << 5) + (((ln >> 2) & 1) << 4);
    const int sxw = ((wv * 16 + ln) << 7) + sxo;
    const int sxr = (((wv ^ 1) * 16 + ln) << 7) + sxo;

    f32x4 O[16];
    #pragma unroll
    for (int i = 0; i < 16; i++) O[i] = (f32x4){0.f, 0.f, 0.f, 0.f};
    float m_reg = -1e30f, l_reg = 0.f;

    for (int it = 0; it < SPK / KT; ++it) {
        char* const KBc = (it & 1) ? KB1 : KB0;
        char* const KBn = (it & 1) ? KB0 : KB1;
        int nkb = ((it + 1) * KT) & (SPK - 1);

        stageK(KBn, nkb);

        asm volatile("s_waitcnt vmcnt(8)" ::: "memory");
        __builtin_amdgcn_s_barrier();

        const char* kE = KBc + BK;
        const char* kO = KBc + (BK ^ 64);
        f32x4 Sa = {0.f,0.f,0.f,0.f}, Sb = {0.f,0.f,0.f,0.f};
        __builtin_amdgcn_s_setprio(1);
        #pragma unroll
        for (int kt = 0; kt < 8; kt++) {
            const char* p = (kt & 1) ? kO : kE;
            bf16x8 k0 = *(const bf16x8*)(p + (kt >> 1) * 128);
            bf16x8 k1 = *(const bf16x8*)(p + (kt >> 1) * 128 + 16384);
            Sa = __builtin_amdgcn_mfma_f32_16x16x32_bf16(k0, qf[kt], Sa, 0, 0, 0);
            Sb = __builtin_amdgcn_mfma_f32_16x16x32_bf16(k1, qf[kt], Sb, 0, 0, 0);
        }
        __builtin_amdgcn_s_setprio(0);

        *(f32x4*)(SX + sxw)        = Sa;
        *(f32x4*)(SX + (sxw ^ 16)) = Sb;
        asm volatile("s_waitcnt vmcnt(4) lgkmcnt(0)" ::: "memory");
        __builtin_amdgcn_s_barrier();
        Sa += *(const f32x4*)(SX + sxr);
        Sb += *(const f32x4*)(SX + (sxr ^ 16));

        float mx = fmaxf(fmaxf(fmaxf(Sa[0],Sa[1]), fmaxf(Sa[2],Sa[3])),
                         fmaxf(fmaxf(Sb[0],Sb[1]), fmaxf(Sb[2],Sb[3])));
        mx = fmaxf(mx, __shfl_xor(mx, 16, 64));
        mx = fmaxf(mx, __shfl_xor(mx, 32, 64));
        if (!__all(mx <= m_reg + 8.f)) {
            float mnew  = fmaxf(m_reg, mx);
            float alpha = __expf(m_reg - mnew);
            l_reg *= alpha;
            #pragma unroll
            for (int ct = 0; ct < 16; ct++) {
                #pragma unroll
                for (int r = 0; r < 4; r++) O[ct][r] *= alpha;
            }
            m_reg = mnew;
        }
        float e0 = __expf(Sa[0]-m_reg), e1 = __expf(Sa[1]-m_reg);
        float e2 = __expf(Sa[2]-m_reg), e3 = __expf(Sa[3]-m_reg);
        float e4 = __expf(Sb[0]-m_reg), e5 = __expf(Sb[1]-m_reg);
        float e6 = __expf(Sb[2]-m_reg), e7 = __expf(Sb[3]-m_reg);
        float ts = ((e0+e1)+(e2+e3)) + ((e4+e5)+(e6+e7));
        ts += __shfl_xor(ts, 16, 64);
        ts += __shfl_xor(ts, 32, 64);
        l_reg += ts;
        bf16x8 pf;
        pf[0] = f2b(e0); pf[1] = f2b(e1); pf[2] = f2b(e2); pf[3] = f2b(e3);
        pf[4] = f2b(e4); pf[5] = f2b(e5); pf[6] = f2b(e6); pf[7] = f2b(e7);

        const char* vp = VB + BV;
        __builtin_amdgcn_s_setprio(1);
        #pragma unroll
        for (int ct = 0; ct < 16; ct++) {
            bf16x8 vv = *(const bf16x8*)(vp + ct * 1024);
            O[ct] = __builtin_amdgcn_mfma_f32_16x16x32_bf16(vv, pf, O[ct], 0, 0, 0);
        }
        __builtin_amdgcn_s_setprio(0);

        asm volatile("s_waitcnt lgkmcnt(0)" ::: "memory");
        __builtin_amdgcn_s_barrier();

        stageV(nkb);
    }
    asm volatile("s_waitcnt vmcnt(0)" ::: "memory");

    size_t n = (size_t)(b * NSP + sp) * NPIX + q0 + qg * 16 + ln;
    unsigned short* Ob = Opart + n * CH + cs * 256 + quad * 4;
    #pragma unroll
    for (int ct = 0; ct < 16; ct++) {
        bf16x4 pk;
        #pragma unroll
        for (int r = 0; r < 4; r++) pk[r] = f2b(O[ct][r]);
        *(bf16x4*)(Ob + ct * 16) = pk;
    }
    if (cs == 0 && quad == 0) {
        ml[n * 2 + 0] = m_reg;
        ml[n * 2 + 1] = l_reg;
    }
}

// ---------------------------------------------------------------- merge 2 splits + proj + residual
// proj weights read via the fragment-major layout (coalesced).
__global__ __launch_bounds__(512, 2) void merge_kernel(
    const float* __restrict__ x,
    const unsigned short* __restrict__ Opart,
    const float* __restrict__ ml,
    const unsigned short* __restrict__ pw,   // bf16 proj_w, fragment-major
    const float* __restrict__ pb,
    float* __restrict__ out)
{
    __shared__ __align__(16) unsigned short ao[32][520];
    int b  = blockIdx.y;
    int q0 = blockIdx.x * 32;
    int tid = threadIdx.x;
    int wv = tid >> 6, lane = tid & 63, ln = lane & 15, quad = lane >> 4;

    {   // combine splits: p = tid&31 (pixel), cs = tid>>5 (16 slots of 8ch)
        int p = tid & 31, cs = tid >> 5;
        int n = q0 + p;
        size_t i0 = ((size_t)(b * NSP + 0) * NPIX + n) * 2;
        size_t i1 = ((size_t)(b * NSP + 1) * NPIX + n) * 2;
        float m0 = ml[i0], l0 = ml[i0 + 1];
        float m1 = ml[i1], l1 = ml[i1 + 1];
        float M  = fmaxf(m0, m1);
        float e0 = __expf(m0 - M), e1 = __expf(m1 - M);
        float den = l0 * e0 + l1 * e1;
        float w0 = e0 / den, w1 = e1 / den;
        const unsigned short* O0 = Opart + ((size_t)(b * NSP + 0) * NPIX + n) * CH;
        const unsigned short* O1 = Opart + ((size_t)(b * NSP + 1) * NPIX + n) * CH;
        #pragma unroll
        for (int k = 0; k < 4; k++) {
            int c = cs * 8 + k * 128;
            bf16x8 a0 = *(const bf16x8*)(O0 + c);
            bf16x8 a1 = *(const bf16x8*)(O1 + c);
            #pragma unroll
            for (int j = 0; j < 8; j++)
                ao[p][c + j] = f2b(b2f((unsigned short)a0[j]) * w0 +
                                   b2f((unsigned short)a1[j]) * w1);
        }
    }
    __syncthreads();

    // ---- proj: out channels [wv*64,+64) + bias + residual (fp32)
    #pragma unroll
    for (int nt = 0; nt < 4; nt++) {
        int o = wv * 64 + nt * 16 + ln;
        int rg = wv * 4 + nt;                     // row-group
        const unsigned short* bp = pw + (size_t)rg * 8192 + quad * 128 + ln * 8;
        bf16x8 wf[16];
        #pragma unroll
        for (int k = 0; k < 16; k++) wf[k] = *(const bf16x8*)(bp + k * 512);
        float bi = pb[o];
        #pragma unroll
        for (int qt = 0; qt < 2; qt++) {
            f32x4 acc = {0.f, 0.f, 0.f, 0.f};
            #pragma unroll
            for (int k = 0; k < 16; k++) {
                bf16x8 a = *(const bf16x8*)(&ao[qt * 16 + ln][quad * 8 + k * 32]);
                acc = __builtin_amdgcn_mfma_f32_16x16x32_bf16(a, wf[k], acc, 0, 0, 0);
            }
            size_t base = ((size_t)b * CH + o) * NPIX + q0 + qt * 16 + quad * 4;
            f32x4 xin = *(const f32x4*)(x + base);
            f32x4 o4;
            #pragma unroll
            for (int r = 0; r < 4; r++) o4[r] = xin[r] + acc[r] + bi;
            *(f32x4*)(out + base) = o4;
        }
    }
}

// ----------------------------------------------------------------
extern "C" void kernel_launch(void* const* d_in, const int* in_sizes, int n_in,
                              void* d_out, int out_size, void* d_ws, size_t ws_size,
                              hipStream_t stream)
{
    const float* x      = (const float*)d_in[0];
    const float* gn_g   = (const float*)d_in[1];
    const float* gn_b   = (const float*)d_in[2];
    const float* qkv_w  = (const float*)d_in[3];
    const float* qkv_b  = (const float*)d_in[4];
    const float* proj_w = (const float*)d_in[5];
    const float* proj_b = (const float*)d_in[6];
    float* out = (float*)d_out;

    // Workspace (shorts): K 4M | V 4M | Q 4M | wbf 1M | part/ml | Opart 8M (~42MB)
    unsigned short* ws  = (unsigned short*)d_ws;
    unsigned short* Kb  = ws;                           // [2][4096][512]
    unsigned short* Vb  = ws + 4u * 1024 * 1024;        // [2][512][4096] (pi-permuted groups)
    unsigned short* Qb  = ws + 8u * 1024 * 1024;        // [2][4096][512] (scaled)
    unsigned short* wbf = ws + 12u * 1024 * 1024;       // qkv_w | proj_w bf16 (fragment-major)
    unsigned short* wp  = wbf + 786432;
    f32x2* part  = (f32x2*)(ws + 13u * 1024 * 1024 + 1024);      // 256 f32x2
    float* ml    = (float*)(ws + 13u * 1024 * 1024 + 4096);      // [2][2][4096][2] f32
    unsigned short* Opart = ws + 13u * 1024 * 1024 + 4096 + 131072;

    convstats_kernel<<<dim3(4096 + 256), 256, 0, stream>>>(qkv_w, proj_w, x, wbf, part);
    qkv_kernel    <<<dim3(NPIX / 64, BATCH, 3), 256, 0, stream>>>(
        x, wbf, qkv_b, gn_g, gn_b, part, Qb, Kb, Vb);
    attn_kernel   <<<dim3(256), 512, 0, stream>>>(Qb, Kb, Vb, Opart, ml);
    merge_kernel  <<<dim3(NPIX / 32, BATCH), 512, 0, stream>>>(
        x, Opart, ml, wp, proj_b, out);
}